// Round 6
// baseline (161.553 us; speedup 1.0000x reference)
//
#include <hip/hip_runtime.h>
#include <hip/hip_bf16.h>
#include <math.h>

#define N_IMG 8192
#define M_TXT 8192
#define DIMK  256
#define BT    128    // output tile (BT x BT)

typedef short bf16x8 __attribute__((ext_vector_type(8)));
typedef float f32x4  __attribute__((ext_vector_type(4)));

__device__ inline void gload_lds16(const void* g, void* l) {
    __builtin_amdgcn_global_load_lds(
        (const __attribute__((address_space(1))) unsigned int*)g,
        (__attribute__((address_space(3))) unsigned int*)l,
        16, 0, 0);
}

// RNE fp32 -> bf16 (inputs finite, |x|<=1 -> no NaN handling needed)
__device__ inline unsigned short f2bf(float x) {
    unsigned u = __float_as_uint(x);
    u += 0x7FFFu + ((u >> 16) & 1u);
    return (unsigned short)(u >> 16);
}

// fp32 -> bf16 with the LDS anti-bank-conflict rotation PRE-APPLIED at the
// global level (global_load_lds writes LDS linearly -> permutation must live
// in the source). K-blocks of 32 elems = 4 chunks of 8 bf16; physical chunk j
// of row r holds logical chunk (j - (r>>1)) & 3. Read side uses slot
// (kg + (r16>>1)) & 3 with kg = lane>>4: HW-verified 0 conflicts (slot offset
// MUST vary at lane>>4 granularity; a lane>>5-only variant measured 4.19M
// conflict cycles). Block 0 also zeroes the accumulators.
__global__ void convert_swz(const float* __restrict__ srcA,
                            const float* __restrict__ srcB,
                            unsigned short* __restrict__ dstA,
                            unsigned short* __restrict__ dstB,
                            double* __restrict__ accums) {
    if (blockIdx.x == 0) {
#pragma unroll
        for (int s = 0; s < 8; ++s) accums[threadIdx.x * 8 + s] = 0.0;
    }
    int q = blockIdx.x * blockDim.x + threadIdx.x;
    const int per = N_IMG * (DIMK / 8);
    const float* src; unsigned short* dst; int qq = q;
    if (q < per) { src = srcA; dst = dstA; }
    else         { src = srcB; dst = dstB; qq = q - per; }
    int r  = qq >> 5, jj = qq & 31;          // 32 chunks per row
    int kb = jj >> 2, j = jj & 3;            // K-block (32 elems), chunk in block
    int c  = (j - (r >> 1)) & 3;             // logical chunk stored here
    const float4* s = (const float4*)(src + (size_t)r * DIMK + kb * 32 + c * 8);
    float4 a = s[0], b = s[1];
    uint4 w;
    w.x = (unsigned)f2bf(a.x) | ((unsigned)f2bf(a.y) << 16);
    w.y = (unsigned)f2bf(a.z) | ((unsigned)f2bf(a.w) << 16);
    w.z = (unsigned)f2bf(b.x) | ((unsigned)f2bf(b.y) << 16);
    w.w = (unsigned)f2bf(b.z) | ((unsigned)f2bf(b.w) << 16);
    ((uint4*)dst)[qq] = w;
}

// Fused NT GEMM (img @ text^T) + multi-similarity masked reduction.
// WHOLE-K-IN-LDS design: K=256 is small enough that the 128x128 tile's full
// A and B slabs (128 KB) fit in LDS at once, in 16 disjoint 8 KB panels
// ([K-block kb][128 rows][32 elems], the HW-proven rotation layout).
// => ZERO buffer reuse => zero WAR hazards => no double-buffering, no lgkm
// drains, no per-K-step barrier pair (rounds 0-5 showed that cadence, not
// VALU or HBM, is the bottleneck: MFMA-busy 14us of 67us with the rest
// barrier/waitcnt structure).
// Schedule: issue labels + ALL 32 staging loads/lane up front (disjoint
// panels), then 4 K64-slabs, each = one counted vmcnt + one barrier + 32
// MFMA/wave with no syncs inside (compiler schedules ds_read ahead freely).
// vmcnt ledger (in-order retirement): labels(8),s0(8),s1(8),s2(8),s3(8)
// -> waits 24/16/8/0 at slab entries. Slab s has ~s*620 cyc of prefetch
// lead; aggregate L2 demand ~20 TB/s < 34.5 TB/s ceiling.
// 1 block/CU, 4 waves (2Mx2N, 64x64 each, acc[4][4]) — low occupancy is
// fine: there is nothing to synchronize against inside the compute phase.
__launch_bounds__(256, 1)
__global__ void msloss_gemm(const unsigned short* __restrict__ Abf,
                            const unsigned short* __restrict__ Bbf,
                            const int* __restrict__ rowLab,
                            const int* __restrict__ colLab,
                            double* __restrict__ accums) {
    __shared__ __align__(16) unsigned short As[8][BT * 32];   // 8 KB / panel
    __shared__ __align__(16) unsigned short Bs[8][BT * 32];   // 64+64 KB

    int tid  = threadIdx.x;
    int wave = tid >> 6, lane = tid & 63;
    int r16  = lane & 15, kg = lane >> 4;
    int wrow = (wave >> 1) * 64, wcol = (wave & 1) * 64;

    // bijective XCD swizzle (4096 blocks, 8 XCDs); within an XCD consecutive
    // blocks walk cols at fixed row -> A-panel L2 reuse.
    int bid = blockIdx.x;
    int swz = (bid & 7) * 512 + (bid >> 3);
    int tileRow = (swz >> 6) * BT;
    int tileCol = (swz & 63) * BT;

    // ---- issue labels first (oldest in vmcnt order; retired by vmcnt(24))
    int tr = tileRow + wrow, tc = tileCol + wcol;
    int4 rl4[4]; int mycl[4];
#pragma unroll
    for (int m = 0; m < 4; ++m)
        rl4[m] = *(const int4*)(rowLab + tr + m * 16 + kg * 4);
#pragma unroll
    for (int n = 0; n < 4; ++n)
        mycl[n] = colLab[tc + n * 16 + r16];

    // ---- stage panel kb of one matrix: 512 chunks of 16B, 2 rounds of 256
    auto STAGE_PANEL = [&](unsigned short* panel, const unsigned short* srcM,
                           int base, int kb) {
#pragma unroll
        for (int i = 0; i < 2; ++i) {
            int p = i * 256 + wave * 64 + lane;      // chunk id 0..511
            int r = p >> 2, j = p & 3;
            gload_lds16(srcM + (size_t)(base + r) * DIMK + kb * 32 + j * 8,
                        panel + (i * 256 + wave * 64) * 8);
        }
    };

    // ---- issue ALL staging, slab order: s = {A(2s),A(2s+1),B(2s),B(2s+1)}
#pragma unroll
    for (int s = 0; s < 4; ++s) {
        STAGE_PANEL(As[2 * s],     Abf, tileRow, 2 * s);
        STAGE_PANEL(As[2 * s + 1], Abf, tileRow, 2 * s + 1);
        STAGE_PANEL(Bs[2 * s],     Bbf, tileCol, 2 * s);
        STAGE_PANEL(Bs[2 * s + 1], Bbf, tileCol, 2 * s + 1);
    }

    f32x4 acc[4][4] = {};
    int slot = ((r16 >> 1) + kg) & 3;

    // ---- 4 K64-slabs: one vmcnt + one barrier each; no syncs inside
#pragma unroll
    for (int s = 0; s < 4; ++s) {
        if (s == 0)      asm volatile("s_waitcnt vmcnt(24)" ::: "memory");
        else if (s == 1) asm volatile("s_waitcnt vmcnt(16)" ::: "memory");
        else if (s == 2) asm volatile("s_waitcnt vmcnt(8)"  ::: "memory");
        else             asm volatile("s_waitcnt vmcnt(0)"  ::: "memory");
        __builtin_amdgcn_s_barrier();            // all waves' slab-s loads in
        __builtin_amdgcn_sched_barrier(0);

#pragma unroll
        for (int th = 0; th < 2; ++th) {
            int t = 2 * s + th;                  // K-block / panel index
            const unsigned short* as = As[t];
            const unsigned short* bs = Bs[t];
            bf16x8 a[4], b[4];
#pragma unroll
            for (int m = 0; m < 4; ++m)
                a[m] = *(const bf16x8*)(as + (wrow + m * 16 + r16) * 32 + slot * 8);
#pragma unroll
            for (int n = 0; n < 4; ++n)
                b[n] = *(const bf16x8*)(bs + (wcol + n * 16 + r16) * 32 + slot * 8);
#pragma unroll
            for (int m = 0; m < 4; ++m)
#pragma unroll
                for (int n = 0; n < 4; ++n)
                    acc[m][n] = __builtin_amdgcn_mfma_f32_16x16x32_bf16(
                        a[m], b[n], acc[m][n], 0, 0, 0);
        }
    }

    // ---- fused epilogue (C/D map: col = lane&15, row = kg*4 + reg) ----
    const float CPOS = -2.8853900817779268f;   //  -2 * log2(e)
    const float CNEG = 57.707801635558536f;    //  40 * log2(e)
    const float DPOS = 1.4426950408889634f;    // -0.5*CPOS
    const float DNEG = -28.853900817779268f;   // -0.5*CNEG
    const float THI  = 0.25f;  // skip thresh: dropped terms <= e^-10 each

    float ps = 0.f, ns = 0.f;
    unsigned posc = 0, pec = 0;                // wave-uniform (SALU) counters
#pragma unroll
    for (int m = 0; m < 4; ++m) {
        int lab[4] = {rl4[m].x, rl4[m].y, rl4[m].z, rl4[m].w};
#pragma unroll
        for (int j = 0; j < 4; ++j) {
            int myrl = lab[j];
#pragma unroll
            for (int n = 0; n < 4; ++n) {
                float v  = acc[m][n][j];
                bool eq  = (myrl == mycl[n]);
                bool pos = v > 0.f;
                unsigned long long bp  = __ballot(pos);
                unsigned long long bpe = bp & __ballot(eq);
                unsigned long long bhi = __ballot(v > THI);
                posc += (unsigned)__popcll(bp);    // SALU
                pec  += (unsigned)__popcll(bpe);   // SALU
                if (__builtin_expect((bool)(bpe | bhi), 0)) {
                    float targ = fmaf(v, eq ? CPOS : CNEG, eq ? DPOS : DNEG);
                    float e    = exp2f(pos ? targ : -100.f);  // !pos -> ~0
                    bool  pe   = pos && eq;
                    ps += pe ? e : 0.f;
                    ns += pe ? 0.f : e;            // !pos lanes add ~0
                }
            }
        }
    }
    // wave reduce (64 lanes) — only the two float sums; counts are uniform
#pragma unroll
    for (int off = 32; off > 0; off >>= 1) {
        ps += __shfl_down(ps, off, 64);
        ns += __shfl_down(ns, off, 64);
    }
    if (lane == 0) {
        double* s = accums + ((((unsigned)bid << 2) | (unsigned)wave) & 255u) * 8;
        atomicAdd(s + 0, (double)ps);
        atomicAdd(s + 1, (double)ns);
        atomicAdd((unsigned long long*)(s + 2), (unsigned long long)pec);
        atomicAdd((unsigned long long*)(s + 3), (unsigned long long)(posc - pec));
    }
}

__global__ void finalize_loss(const double* __restrict__ accums,
                              float* __restrict__ out) {
    int lane = threadIdx.x;
    double ps = 0, ns = 0, pc = 0, nc = 0;
#pragma unroll
    for (int s = lane; s < 256; s += 64) {
        ps += accums[s * 8 + 0];
        ns += accums[s * 8 + 1];
        pc += (double)((const unsigned long long*)accums)[s * 8 + 2];
        nc += (double)((const unsigned long long*)accums)[s * 8 + 3];
    }
#pragma unroll
    for (int off = 32; off > 0; off >>= 1) {
        ps += __shfl_down(ps, off, 64);
        ns += __shfl_down(ns, off, 64);
        pc += __shfl_down(pc, off, 64);
        nc += __shfl_down(nc, off, 64);
    }
    if (lane == 0) {
        double pl = (pc > 0.0) ? log1p(ps) / (2.0 * pc)  : 0.0;
        double nl = (nc > 0.0) ? log1p(ns) / (40.0 * nc) : 0.0;
        out[0] = (float)(pl + nl);
    }
}

extern "C" void kernel_launch(void* const* d_in, const int* in_sizes, int n_in,
                              void* d_out, int out_size, void* d_ws, size_t ws_size,
                              hipStream_t stream) {
    (void)in_sizes; (void)n_in; (void)out_size;
    const float* img    = (const float*)d_in[0];
    const float* txt    = (const float*)d_in[1];
    const int*   gt_pre = (const int*)d_in[2];
    const int*   gt_map = (const int*)d_in[3];
    float* out = (float*)d_out;

    const size_t ACC_BYTES = 256 * 8 * sizeof(double);   // 16 KB, 64B slots
    const size_t MAT_BYTES = (size_t)N_IMG * DIMK * 2;   // 4 MB each
    if (ws_size < ACC_BYTES + 2 * MAT_BYTES) return;

    double*         accums = (double*)d_ws;
    unsigned short* Abf = (unsigned short*)((char*)d_ws + ACC_BYTES);
    unsigned short* Bbf = (unsigned short*)((char*)d_ws + ACC_BYTES + MAT_BYTES);

    int nchunks = 2 * N_IMG * (DIMK / 8);
    convert_swz<<<nchunks / 256, 256, 0, stream>>>(img, txt, Abf, Bbf, accums);
    msloss_gemm<<<(N_IMG / BT) * (M_TXT / BT), 256, 0, stream>>>(Abf, Bbf, gt_pre, gt_map, accums);
    finalize_loss<<<1, 64, 0, stream>>>(accums, out);
}

// Round 7
// 103.883 us; speedup vs baseline: 1.5551x; 1.5551x over previous
//
#include <hip/hip_runtime.h>
#include <hip/hip_bf16.h>
#include <math.h>

#define N_IMG 8192
#define M_TXT 8192
#define DIMK  256
#define BM    256    // output tile rows
#define BN    256    // output tile cols
#define BKT   64     // K per LDS tile (2 panels of 32); 4 tiles cover K=256

typedef short bf16x8 __attribute__((ext_vector_type(8)));
typedef float f32x4  __attribute__((ext_vector_type(4)));

__device__ inline void gload_lds16(const void* g, void* l) {
    __builtin_amdgcn_global_load_lds(
        (const __attribute__((address_space(1))) unsigned int*)g,
        (__attribute__((address_space(3))) unsigned int*)l,
        16, 0, 0);
}

// RNE fp32 -> bf16 (inputs finite, |x|<=1 -> no NaN handling needed)
__device__ inline unsigned short f2bf(float x) {
    unsigned u = __float_as_uint(x);
    u += 0x7FFFu + ((u >> 16) & 1u);
    return (unsigned short)(u >> 16);
}

// fp32 -> bf16 with the LDS anti-bank-conflict rotation PRE-APPLIED at the
// global level (global_load_lds writes LDS linearly -> permutation must live
// in the source). K-blocks of 32 elems = 4 chunks of 8 bf16; physical chunk j
// of row r holds logical chunk (j - (r>>1)) & 3. Read side uses slot
// (kg + (r16>>1)) & 3 with kg = lane>>4: HW-verified 0 conflicts (slot offset
// MUST vary at lane>>4 granularity; a lane>>5-only variant measured 4.19M
// conflict cycles). Valid for any tile geometry with row/col bases == 0 mod 8.
// Block 0 also zeroes the accumulators.
__global__ void convert_swz(const float* __restrict__ srcA,
                            const float* __restrict__ srcB,
                            unsigned short* __restrict__ dstA,
                            unsigned short* __restrict__ dstB,
                            double* __restrict__ accums) {
    if (blockIdx.x == 0) {
#pragma unroll
        for (int s = 0; s < 8; ++s) accums[threadIdx.x * 8 + s] = 0.0;
    }
    int q = blockIdx.x * blockDim.x + threadIdx.x;
    const int per = N_IMG * (DIMK / 8);
    const float* src; unsigned short* dst; int qq = q;
    if (q < per) { src = srcA; dst = dstA; }
    else         { src = srcB; dst = dstB; qq = q - per; }
    int r  = qq >> 5, jj = qq & 31;          // 32 chunks per row
    int kb = jj >> 2, j = jj & 3;            // K-block (32 elems), chunk in block
    int c  = (j - (r >> 1)) & 3;             // logical chunk stored here
    const float4* s = (const float4*)(src + (size_t)r * DIMK + kb * 32 + c * 8);
    float4 a = s[0], b = s[1];
    uint4 w;
    w.x = (unsigned)f2bf(a.x) | ((unsigned)f2bf(a.y) << 16);
    w.y = (unsigned)f2bf(a.z) | ((unsigned)f2bf(a.w) << 16);
    w.z = (unsigned)f2bf(b.x) | ((unsigned)f2bf(b.y) << 16);
    w.w = (unsigned)f2bf(b.z) | ((unsigned)f2bf(b.w) << 16);
    ((uint4*)dst)[qq] = w;
}

// Fused NT GEMM (img @ text^T) + multi-similarity masked reduction.
// Design from rounds 0-6 ablations (requirements: >=2 waves/SIMD [r6];
// staging overlapped via counted vmcnt [r0 vs r6]; proven panel format [r1];
// no occupancy give-back [r2/r4]; MORE MFMA per sync period [r0=67us at 16
// MFMA/wave/barrier-pair was the bottleneck]):
//   256x256 tile, 512 thr / 8 waves (2Mx4N, 2 waves/SIMD), K-tile = 64 held
//   whole in one of 2 LDS slots (64 KB each, 128 KB total, 1 block/CU).
//   Per iteration (one K-tile): 64 MFMA/wave with ZERO internal syncs (the
//   slot is immutable while read). Sync cost: entry = counted vmcnt + 1
//   barrier (publish staged tile); exit = lgkmcnt(0) + 1 barrier (all reads
//   done) then issue stage of tile t+2 into the freed slot -> its latency is
//   covered by the whole next iteration (~2.5k cyc >> L2 ~600).
// vmcnt ledger (panel = 8 KB = 1 load/lane @512thr; 8 panels/tile):
//   prologue: T0(8),T1(8) -> wait vmcnt(8) [T0 done]
//   iter0 end: stage T2 | iter1 entry: vmcnt(8) [T1 done]
//   iter1 end: stage T3 | iter2 entry: vmcnt(8) [T2 done]
//   iter2 end: labels(12) | iter3 entry: vmcnt(12) [T3 done]
//   epilogue: vmcnt(0) [labels done]
__launch_bounds__(512, 2)
__global__ void msloss_gemm(const unsigned short* __restrict__ Abf,
                            const unsigned short* __restrict__ Bbf,
                            const int* __restrict__ rowLab,
                            const int* __restrict__ colLab,
                            double* __restrict__ accums) {
    // [slot][rowhalf][kb-in-tile][128 rows x 32 elems]  (8 KB panels)
    __shared__ __align__(16) unsigned short As[2][2][2][128 * 32];   // 64 KB
    __shared__ __align__(16) unsigned short Bs[2][2][2][128 * 32];   // 64 KB

    int tid  = threadIdx.x;
    int wave = tid >> 6, lane = tid & 63;
    int r16  = lane & 15, kg = lane >> 4;
    int wm   = wave >> 2;            // 0..1: 128-row strip
    int wn   = wave & 3;             // 0..3: 64-col strip

    // bijective XCD swizzle (1024 blocks, 8 XCDs); within an XCD consecutive
    // blocks walk cols at fixed row -> A-panel L2 reuse.
    int bid = blockIdx.x;
    int swz = (bid & 7) * 128 + (bid >> 3);
    int tileRow = (swz >> 5) * BM;
    int tileCol = (swz & 31) * BN;

    auto PANEL = [&](unsigned short* dst, const unsigned short* srcM,
                     int growBase, int kbg) {
        int p = tid;                         // chunk id 0..511 (1 load/lane)
        int r = p >> 2, j = p & 3;
        gload_lds16(srcM + (size_t)(growBase + r) * DIMK + kbg * 32 + j * 8,
                    dst + wave * 512);       // HW adds lane*16B
    };
    auto STAGE_TILE = [&](int s, int t) {    // 8 loads/lane
        PANEL(&As[s][0][0][0], Abf, tileRow,        2 * t);
        PANEL(&As[s][0][1][0], Abf, tileRow,        2 * t + 1);
        PANEL(&As[s][1][0][0], Abf, tileRow + 128,  2 * t);
        PANEL(&As[s][1][1][0], Abf, tileRow + 128,  2 * t + 1);
        PANEL(&Bs[s][0][0][0], Bbf, tileCol,        2 * t);
        PANEL(&Bs[s][0][1][0], Bbf, tileCol,        2 * t + 1);
        PANEL(&Bs[s][1][0][0], Bbf, tileCol + 128,  2 * t);
        PANEL(&Bs[s][1][1][0], Bbf, tileCol + 128,  2 * t + 1);
    };

    f32x4 acc[8][4] = {};
    int rot = ((r16 >> 1) + kg) & 3;

    // per-wave output 128x64: acc[mm][nn] <-> row wm*128+mm*16, col wn*64+nn*16
    auto COMPUTE_TILE = [&](int s) {
#pragma unroll
        for (int q = 0; q < 4; ++q) {        // quadrant: 4m x 2n x 2kb = 16 MFMA
            int mh = q >> 1, nh = q & 1;
            int colbase = wn * 64 + nh * 32;
            int bh = colbase >> 7, rb = colbase & 127;
            bf16x8 a[2][4], b[2][2];
#pragma unroll
            for (int bb = 0; bb < 2; ++bb)
#pragma unroll
                for (int i = 0; i < 4; ++i)
                    a[bb][i] = *(const bf16x8*)(&As[s][wm][bb][0]
                               + (mh * 64 + i * 16 + r16) * 32 + rot * 8);
#pragma unroll
            for (int bb = 0; bb < 2; ++bb)
#pragma unroll
                for (int n = 0; n < 2; ++n)
                    b[bb][n] = *(const bf16x8*)(&Bs[s][bh][bb][0]
                               + (rb + n * 16 + r16) * 32 + rot * 8);
#pragma unroll
            for (int bb = 0; bb < 2; ++bb)
#pragma unroll
                for (int i = 0; i < 4; ++i)
#pragma unroll
                    for (int n = 0; n < 2; ++n)
                        acc[mh * 4 + i][nh * 2 + n] =
                            __builtin_amdgcn_mfma_f32_16x16x32_bf16(
                                a[bb][i], b[bb][n],
                                acc[mh * 4 + i][nh * 2 + n], 0, 0, 0);
        }
    };

    STAGE_TILE(0, 0);
    STAGE_TILE(1, 1);

    int4 rl4[8]; int mycl[4];

    // iter 0 (slot 0, tile 0)
    asm volatile("s_waitcnt vmcnt(8)" ::: "memory");
    __builtin_amdgcn_s_barrier();
    __builtin_amdgcn_sched_barrier(0);
    COMPUTE_TILE(0);
    asm volatile("s_waitcnt lgkmcnt(0)" ::: "memory");
    __builtin_amdgcn_sched_barrier(0);
    __builtin_amdgcn_s_barrier();
    __builtin_amdgcn_sched_barrier(0);
    STAGE_TILE(0, 2);

    // iter 1 (slot 1, tile 1)
    asm volatile("s_waitcnt vmcnt(8)" ::: "memory");
    __builtin_amdgcn_s_barrier();
    __builtin_amdgcn_sched_barrier(0);
    COMPUTE_TILE(1);
    asm volatile("s_waitcnt lgkmcnt(0)" ::: "memory");
    __builtin_amdgcn_sched_barrier(0);
    __builtin_amdgcn_s_barrier();
    __builtin_amdgcn_sched_barrier(0);
    STAGE_TILE(1, 3);

    // iter 2 (slot 0, tile 2)
    asm volatile("s_waitcnt vmcnt(8)" ::: "memory");
    __builtin_amdgcn_s_barrier();
    __builtin_amdgcn_sched_barrier(0);
    COMPUTE_TILE(0);
    asm volatile("s_waitcnt lgkmcnt(0)" ::: "memory");
    __builtin_amdgcn_sched_barrier(0);
    __builtin_amdgcn_s_barrier();
    __builtin_amdgcn_sched_barrier(0);
    // labels (12 loads, newest in vmcnt order; drained at epilogue vmcnt(0))
    {
        int tr = tileRow + wm * 128, tc = tileCol + wn * 64;
#pragma unroll
        for (int m = 0; m < 8; ++m)
            rl4[m] = *(const int4*)(rowLab + tr + m * 16 + kg * 4);
#pragma unroll
        for (int n = 0; n < 4; ++n)
            mycl[n] = colLab[tc + n * 16 + r16];
    }

    // iter 3 (slot 1, tile 3)
    asm volatile("s_waitcnt vmcnt(12)" ::: "memory");  // T3 done; labels fly
    __builtin_amdgcn_s_barrier();
    __builtin_amdgcn_sched_barrier(0);
    COMPUTE_TILE(1);

    asm volatile("s_waitcnt vmcnt(0)" ::: "memory");   // labels landed

    // ---- fused epilogue (C/D map: col = lane&15, row = kg*4 + reg) ----
    const float CPOS = -2.8853900817779268f;   //  -2 * log2(e)
    const float CNEG = 57.707801635558536f;    //  40 * log2(e)
    const float DPOS = 1.4426950408889634f;    // -0.5*CPOS
    const float DNEG = -28.853900817779268f;   // -0.5*CNEG
    const float THI  = 0.25f;  // skip thresh: dropped terms <= e^-10 each

    float ps = 0.f, ns = 0.f;
    unsigned posc = 0, pec = 0;                // wave-uniform (SALU) counters
#pragma unroll
    for (int m = 0; m < 8; ++m) {
        int lab[4] = {rl4[m].x, rl4[m].y, rl4[m].z, rl4[m].w};
#pragma unroll
        for (int j = 0; j < 4; ++j) {
            int myrl = lab[j];
#pragma unroll
            for (int n = 0; n < 4; ++n) {
                float v  = acc[m][n][j];
                bool eq  = (myrl == mycl[n]);
                bool pos = v > 0.f;
                unsigned long long bp  = __ballot(pos);
                unsigned long long bpe = bp & __ballot(eq);
                unsigned long long bhi = __ballot(v > THI);
                posc += (unsigned)__popcll(bp);    // SALU
                pec  += (unsigned)__popcll(bpe);   // SALU
                if (__builtin_expect((bool)(bpe | bhi), 0)) {
                    float targ = fmaf(v, eq ? CPOS : CNEG, eq ? DPOS : DNEG);
                    float e    = exp2f(pos ? targ : -100.f);  // !pos -> ~0
                    bool  pe   = pos && eq;
                    ps += pe ? e : 0.f;
                    ns += pe ? 0.f : e;            // !pos lanes add ~0
                }
            }
        }
    }
    // wave reduce (64 lanes) — only the two float sums; counts are uniform
#pragma unroll
    for (int off = 32; off > 0; off >>= 1) {
        ps += __shfl_down(ps, off, 64);
        ns += __shfl_down(ns, off, 64);
    }
    if (lane == 0) {
        double* s = accums + ((((unsigned)bid << 3) | (unsigned)wave) & 255u) * 8;
        atomicAdd(s + 0, (double)ps);
        atomicAdd(s + 1, (double)ns);
        atomicAdd((unsigned long long*)(s + 2), (unsigned long long)pec);
        atomicAdd((unsigned long long*)(s + 3), (unsigned long long)(posc - pec));
    }
}

__global__ void finalize_loss(const double* __restrict__ accums,
                              float* __restrict__ out) {
    int lane = threadIdx.x;
    double ps = 0, ns = 0, pc = 0, nc = 0;
#pragma unroll
    for (int s = lane; s < 256; s += 64) {
        ps += accums[s * 8 + 0];
        ns += accums[s * 8 + 1];
        pc += (double)((const unsigned long long*)accums)[s * 8 + 2];
        nc += (double)((const unsigned long long*)accums)[s * 8 + 3];
    }
#pragma unroll
    for (int off = 32; off > 0; off >>= 1) {
        ps += __shfl_down(ps, off, 64);
        ns += __shfl_down(ns, off, 64);
        pc += __shfl_down(pc, off, 64);
        nc += __shfl_down(nc, off, 64);
    }
    if (lane == 0) {
        double pl = (pc > 0.0) ? log1p(ps) / (2.0 * pc)  : 0.0;
        double nl = (nc > 0.0) ? log1p(ns) / (40.0 * nc) : 0.0;
        out[0] = (float)(pl + nl);
    }
}

extern "C" void kernel_launch(void* const* d_in, const int* in_sizes, int n_in,
                              void* d_out, int out_size, void* d_ws, size_t ws_size,
                              hipStream_t stream) {
    (void)in_sizes; (void)n_in; (void)out_size;
    const float* img    = (const float*)d_in[0];
    const float* txt    = (const float*)d_in[1];
    const int*   gt_pre = (const int*)d_in[2];
    const int*   gt_map = (const int*)d_in[3];
    float* out = (float*)d_out;

    const size_t ACC_BYTES = 256 * 8 * sizeof(double);   // 16 KB, 64B slots
    const size_t MAT_BYTES = (size_t)N_IMG * DIMK * 2;   // 4 MB each
    if (ws_size < ACC_BYTES + 2 * MAT_BYTES) return;

    double*         accums = (double*)d_ws;
    unsigned short* Abf = (unsigned short*)((char*)d_ws + ACC_BYTES);
    unsigned short* Bbf = (unsigned short*)((char*)d_ws + ACC_BYTES + MAT_BYTES);

    int nchunks = 2 * N_IMG * (DIMK / 8);
    convert_swz<<<nchunks / 256, 256, 0, stream>>>(img, txt, Abf, Bbf, accums);
    msloss_gemm<<<(N_IMG / BM) * (M_TXT / BN), 512, 0, stream>>>(Abf, Bbf, gt_pre, gt_map, accums);
    finalize_loss<<<1, 64, 0, stream>>>(accums, out);
}

// Round 8
// 92.396 us; speedup vs baseline: 1.7485x; 1.1243x over previous
//
#include <hip/hip_runtime.h>
#include <hip/hip_bf16.h>
#include <math.h>

#define N_IMG 8192
#define M_TXT 8192
#define DIMK  256
#define BT    128    // output tile (BT x BT)
#define BK    32     // K-step
#define GRID  768    // 3 blocks/CU exactly; work distributed by tickets
#define TPG   512    // tiles per XCD group (4096 / 8)

typedef short bf16x8 __attribute__((ext_vector_type(8)));
typedef float f32x4  __attribute__((ext_vector_type(4)));

__device__ inline void gload_lds16(const void* g, void* l) {
    __builtin_amdgcn_global_load_lds(
        (const __attribute__((address_space(1))) unsigned int*)g,
        (__attribute__((address_space(3))) unsigned int*)l,
        16, 0, 0);
}

// RNE fp32 -> bf16 (inputs finite, |x|<=1 -> no NaN handling needed)
__device__ inline unsigned short f2bf(float x) {
    unsigned u = __float_as_uint(x);
    u += 0x7FFFu + ((u >> 16) & 1u);
    return (unsigned short)(u >> 16);
}

// fp32 -> bf16 with the LDS anti-bank-conflict rotation PRE-APPLIED at the
// global level (global_load_lds writes LDS linearly -> permutation must live
// in the source). K-blocks of 32 elems = 4 chunks of 8 bf16; physical chunk j
// of row r holds logical chunk (j - (r>>1)) & 3. Read side uses slot
// (kg + (r16>>1)) & 3 with kg = lane>>4: HW-verified 0 conflicts (slot offset
// MUST vary at lane>>4 granularity; a lane>>5-only variant measured 4.19M
// conflict cycles). Block 0 also zeroes accums and inits ticket/done ctl.
__global__ void convert_swz(const float* __restrict__ srcA,
                            const float* __restrict__ srcB,
                            unsigned short* __restrict__ dstA,
                            unsigned short* __restrict__ dstB,
                            double* __restrict__ accums,
                            int* __restrict__ ctl) {
    if (blockIdx.x == 0) {
#pragma unroll
        for (int s = 0; s < 8; ++s) accums[threadIdx.x * 8 + s] = 0.0;
        if (threadIdx.x < 8)  ctl[threadIdx.x * 32] = GRID / 8;  // tickets: 96
        if (threadIdx.x == 8) ctl[256] = 0;                      // done counter
    }
    int q = blockIdx.x * blockDim.x + threadIdx.x;
    const int per = N_IMG * (DIMK / 8);
    const float* src; unsigned short* dst; int qq = q;
    if (q < per) { src = srcA; dst = dstA; }
    else         { src = srcB; dst = dstB; qq = q - per; }
    int r  = qq >> 5, jj = qq & 31;          // 32 chunks per row
    int kb = jj >> 2, j = jj & 3;            // K-block (32 elems), chunk in block
    int c  = (j - (r >> 1)) & 3;             // logical chunk stored here
    const float4* s = (const float4*)(src + (size_t)r * DIMK + kb * 32 + c * 8);
    float4 a = s[0], b = s[1];
    uint4 w;
    w.x = (unsigned)f2bf(a.x) | ((unsigned)f2bf(a.y) << 16);
    w.y = (unsigned)f2bf(a.z) | ((unsigned)f2bf(a.w) << 16);
    w.z = (unsigned)f2bf(b.x) | ((unsigned)f2bf(b.y) << 16);
    w.w = (unsigned)f2bf(b.z) | ((unsigned)f2bf(b.w) << 16);
    ((uint4*)dst)[qq] = w;
}

// Fused NT GEMM (img @ text^T) + multi-similarity masked reduction.
// r3's proven core (128x128 tile, 4 waves, 16x16x32, dbuf LDS, 2 barriers +
// counted vmcnt per K-step) + TICKET-BASED persistent blocks:
//  - grid = 768 (3/CU); per-XCD-group ticket counters; block bid&7 processes
//    tiles swz = grp*512 + idx (idx = bid>>3 initially, then popped) -> exact
//    r3 XCD locality, self-balancing (fixes r4's solo-generation collapse),
//    and phase-decorrelated blocks (restores m114 boundary hiding).
//  - cross-tile prefetch (r4-validated): at t7 stage next tile's buf0 +
//    labels; they fly across the epilogue.
//  - vmcnt ledger (in-order retirement, 4 loads per STAGE, 8 label loads,
//    4 epilogue atomics, 1 ticket atomic on wave0):
//      prologue: stage0(4)+labels(8)=12
//      t0: +stage1 -> 16 -> vmcnt(12) [first] / prevN0+lab+atom+stage1=20
//          -> vmcnt(16) [else; drains prev tile's stage0]
//      t1: +stage2 -> vmcnt(4) (drains labels/atomics/stage1; all >=1 step old)
//          wave0 lane0 pops ticket AFTER the wait (appended after stage2)
//      t2: +stage3 -> wave0: stage2+tkt+stage3=9, vmcnt(4) drains stage2+tkt
//          (others: 8 -> 4); wave0 publishes tkt to LDS pre-barrier
//      t3-6: vmcnt(4)
//      t7: [if next: +stageN0(4)+labels(8)] -> 16 -> vmcnt(12) [drains stage7]
//          else vmcnt(0)
// Last finishing block (done-counter) runs the final reduction inline.
__launch_bounds__(256, 3)
__global__ void msloss_gemm(const unsigned short* __restrict__ Abf,
                            const unsigned short* __restrict__ Bbf,
                            const int* __restrict__ rowLab,
                            const int* __restrict__ colLab,
                            double* __restrict__ accums,
                            int* __restrict__ ctl,
                            float* __restrict__ out) {
    __shared__ __align__(16) unsigned short As[2][BT * BK];   // 8 KB each
    __shared__ __align__(16) unsigned short Bs[2][BT * BK];
    __shared__ int sNext;

    int tid  = threadIdx.x;
    int wave = tid >> 6, lane = tid & 63;
    int r16  = lane & 15, kg = lane >> 4;
    int wrow = (wave >> 1) * 64, wcol = (wave & 1) * 64;

    int bid = blockIdx.x;
    int grp = bid & 7;
    int* ticket  = ctl + grp * 32;      // 128B-separated counters
    int* doneCnt = ctl + 256;

    auto COORD = [&](int idxv, int& rr, int& cc) {
        int swz = grp * TPG + idxv;     // 0..4095
        rr = (swz >> 6) * BT;
        cc = (swz & 63) * BT;
    };
    auto STAGE = [&](int sel, int k0, int trow, int tcol) {
#pragma unroll
        for (int i = 0; i < 2; ++i) {
            int p = wave * 128 + i * 64 + lane;      // chunk id 0..511
            int r = p >> 2, j = p & 3;
            gload_lds16(Abf + (size_t)(trow + r) * DIMK + k0 + j * 8,
                        &As[sel][(wave * 128 + i * 64) * 8]);
        }
#pragma unroll
        for (int i = 0; i < 2; ++i) {
            int p = wave * 128 + i * 64 + lane;
            int r = p >> 2, j = p & 3;
            gload_lds16(Bbf + (size_t)(tcol + r) * DIMK + k0 + j * 8,
                        &Bs[sel][(wave * 128 + i * 64) * 8]);
        }
    };

    int idx = bid >> 3;                 // initial tile index in group (0..95)
    int tileRow, tileCol;
    COORD(idx, tileRow, tileCol);

    int4 rl4[4], rl4n[4]; int mycl[4], mycln[4];
    auto LOADLAB = [&](int trow, int tcol, int4* R, int* C) {
#pragma unroll
        for (int m = 0; m < 4; ++m)
            R[m] = *(const int4*)(rowLab + trow + wrow + m * 16 + kg * 4);
#pragma unroll
        for (int n = 0; n < 4; ++n)
            C[n] = colLab[tcol + wcol + n * 16 + r16];
    };

    const float CPOS = -2.8853900817779268f;   //  -2 * log2(e)
    const float CNEG = 57.707801635558536f;    //  40 * log2(e)
    const float DPOS = 1.4426950408889634f;    // -0.5*CPOS
    const float DNEG = -28.853900817779268f;   // -0.5*CNEG
    const float THI  = 0.25f;  // skip thresh: dropped terms <= e^-10 each

    STAGE(0, 0, tileRow, tileCol);
    LOADLAB(tileRow, tileCol, rl4, mycl);

    bool first = true;
    int nIdx = TPG, tkt = TPG;
    int slot = ((r16 >> 1) + kg) & 3;

    for (;;) {                                   // per owned tile
        f32x4 acc[4][4] = {};
        int nRow = 0, nCol = 0;

#pragma unroll 1
        for (int t = 0; t < 8; ++t) {
            if (t < 7) {
                STAGE((t + 1) & 1, (t + 1) * BK, tileRow, tileCol);
            } else if (nIdx < TPG) {
                COORD(nIdx, nRow, nCol);
                STAGE(0, 0, nRow, nCol);
                LOADLAB(nRow, nCol, rl4n, mycln);
            }
            if (t == 0) {
                if (first) asm volatile("s_waitcnt vmcnt(12)" ::: "memory");
                else       asm volatile("s_waitcnt vmcnt(16)" ::: "memory");
            } else if (t < 7) {
                asm volatile("s_waitcnt vmcnt(4)" ::: "memory");
            } else if (nIdx < TPG) {
                asm volatile("s_waitcnt vmcnt(12)" ::: "memory");
            } else {
                asm volatile("s_waitcnt vmcnt(0)" ::: "memory");
            }
            __builtin_amdgcn_s_barrier();
            __builtin_amdgcn_sched_barrier(0);

            if (t == 1 && tid == 0)
                tkt = atomicAdd(ticket, 1);      // drained by t2's vmcnt(4)

            const unsigned short* as = As[t & 1];
            const unsigned short* bs = Bs[t & 1];
            bf16x8 a[4], b[4];
#pragma unroll
            for (int m = 0; m < 4; ++m)
                a[m] = *(const bf16x8*)(as + (wrow + m * 16 + r16) * BK + slot * 8);
#pragma unroll
            for (int n = 0; n < 4; ++n)
                b[n] = *(const bf16x8*)(bs + (wcol + n * 16 + r16) * BK + slot * 8);
#pragma unroll
            for (int m = 0; m < 4; ++m)
#pragma unroll
                for (int n = 0; n < 4; ++n)
                    acc[m][n] = __builtin_amdgcn_mfma_f32_16x16x32_bf16(
                        a[m], b[n], acc[m][n], 0, 0, 0);

            if (t == 2 && tid == 0) sNext = tkt; // value ready (entry wait)

            asm volatile("s_waitcnt lgkmcnt(0)" ::: "memory");
            __builtin_amdgcn_sched_barrier(0);
            __builtin_amdgcn_s_barrier();

            if (t == 2) nIdx = sNext;            // published by t2 barrier
        }

        // ---- fused epilogue (C/D map: col = lane&15, row = kg*4 + reg) ----
        // Runs while next tile's stage0/labels are in flight.
        float ps = 0.f, ns = 0.f;
        unsigned posc = 0, pec = 0;              // wave-uniform (SALU)
#pragma unroll
        for (int m = 0; m < 4; ++m) {
            int lab[4] = {rl4[m].x, rl4[m].y, rl4[m].z, rl4[m].w};
#pragma unroll
            for (int j = 0; j < 4; ++j) {
                int myrl = lab[j];
#pragma unroll
                for (int n = 0; n < 4; ++n) {
                    float v  = acc[m][n][j];
                    bool eq  = (myrl == mycl[n]);
                    bool pos = v > 0.f;
                    unsigned long long bp  = __ballot(pos);
                    unsigned long long bpe = bp & __ballot(eq);
                    unsigned long long bhi = __ballot(v > THI);
                    posc += (unsigned)__popcll(bp);
                    pec  += (unsigned)__popcll(bpe);
                    if (__builtin_expect((bool)(bpe | bhi), 0)) {
                        float targ = fmaf(v, eq ? CPOS : CNEG, eq ? DPOS : DNEG);
                        float e    = exp2f(pos ? targ : -100.f);
                        bool  pe   = pos && eq;
                        ps += pe ? e : 0.f;
                        ns += pe ? 0.f : e;
                    }
                }
            }
        }
#pragma unroll
        for (int off = 32; off > 0; off >>= 1) {
            ps += __shfl_down(ps, off, 64);
            ns += __shfl_down(ns, off, 64);
        }
        if (lane == 0) {
            double* s = accums + ((((unsigned)bid << 2) | (unsigned)wave) & 255u) * 8;
            atomicAdd(s + 0, (double)ps);
            atomicAdd(s + 1, (double)ns);
            atomicAdd((unsigned long long*)(s + 2), (unsigned long long)pec);
            atomicAdd((unsigned long long*)(s + 3), (unsigned long long)(posc - pec));
        }

        if (nIdx >= TPG) break;
        tileRow = nRow; tileCol = nCol;
#pragma unroll
        for (int m = 0; m < 4; ++m) rl4[m] = rl4n[m];
#pragma unroll
        for (int n = 0; n < 4; ++n) mycl[n] = mycln[n];
        first = false;
    }

    // ---- last-done block runs the final reduction inline ----
    asm volatile("s_waitcnt vmcnt(0)" ::: "memory");   // my atomics retired
    __builtin_amdgcn_s_barrier();                      // all waves' atomics
    if (wave == 0) {
        int old = 0;
        if (lane == 0)
            old = __hip_atomic_fetch_add(doneCnt, 1, __ATOMIC_ACQ_REL,
                                         __HIP_MEMORY_SCOPE_AGENT);
        old = __shfl(old, 0, 64);
        if (old == GRID - 1) {
            double fps = 0, fns = 0, fpc = 0, fnc = 0;
#pragma unroll
            for (int s = lane; s < 256; s += 64) {
                fps += __hip_atomic_load(&accums[s * 8 + 0], __ATOMIC_RELAXED,
                                         __HIP_MEMORY_SCOPE_AGENT);
                fns += __hip_atomic_load(&accums[s * 8 + 1], __ATOMIC_RELAXED,
                                         __HIP_MEMORY_SCOPE_AGENT);
                fpc += (double)__hip_atomic_load(
                    (unsigned long long*)&accums[s * 8 + 2], __ATOMIC_RELAXED,
                    __HIP_MEMORY_SCOPE_AGENT);
                fnc += (double)__hip_atomic_load(
                    (unsigned long long*)&accums[s * 8 + 3], __ATOMIC_RELAXED,
                    __HIP_MEMORY_SCOPE_AGENT);
            }
#pragma unroll
            for (int off = 32; off > 0; off >>= 1) {
                fps += __shfl_down(fps, off, 64);
                fns += __shfl_down(fns, off, 64);
                fpc += __shfl_down(fpc, off, 64);
                fnc += __shfl_down(fnc, off, 64);
            }
            if (lane == 0) {
                double pl = (fpc > 0.0) ? log1p(fps) / (2.0 * fpc)  : 0.0;
                double nl = (fnc > 0.0) ? log1p(fns) / (40.0 * fnc) : 0.0;
                out[0] = (float)(pl + nl);
            }
        }
    }
}

extern "C" void kernel_launch(void* const* d_in, const int* in_sizes, int n_in,
                              void* d_out, int out_size, void* d_ws, size_t ws_size,
                              hipStream_t stream) {
    (void)in_sizes; (void)n_in; (void)out_size;
    const float* img    = (const float*)d_in[0];
    const float* txt    = (const float*)d_in[1];
    const int*   gt_pre = (const int*)d_in[2];
    const int*   gt_map = (const int*)d_in[3];
    float* out = (float*)d_out;

    const size_t ACC_BYTES = 256 * 8 * sizeof(double);   // 16 KB, 64B slots
    const size_t CTL_BYTES = 2048;                       // tickets + done
    const size_t MAT_BYTES = (size_t)N_IMG * DIMK * 2;   // 4 MB each
    if (ws_size < ACC_BYTES + CTL_BYTES + 2 * MAT_BYTES) return;

    double* accums = (double*)d_ws;
    int*    ctl    = (int*)((char*)d_ws + ACC_BYTES);
    unsigned short* Abf = (unsigned short*)((char*)d_ws + ACC_BYTES + CTL_BYTES);
    unsigned short* Bbf = (unsigned short*)((char*)d_ws + ACC_BYTES + CTL_BYTES + MAT_BYTES);

    int nchunks = 2 * N_IMG * (DIMK / 8);
    convert_swz<<<nchunks / 256, 256, 0, stream>>>(img, txt, Abf, Bbf, accums, ctl);
    msloss_gemm<<<GRID, 256, 0, stream>>>(Abf, Bbf, gt_pre, gt_map, accums, ctl, out);
}